// Round 4
// baseline (492.326 us; speedup 1.0000x reference)
//
#include <hip/hip_runtime.h>
#include <math.h>

#define HH 128
#define WW 128
#define NIMG 4
#define PP 11
#define KSIM 16
#define STRIDE_S 3
#define VRAD 32
#define WINW 65             // 2V+1
#define NTASK (WINW*9)      // 585 tasks: (drx, 8-wide dc strip)
#define HREF 40
#define WREF 40
#define NPOS 118            // H-P+1
#define WROWS 75            // 2V+P
#define WPITCH 84           // rows 336B -> 16B-aligned; c0=8g -> 32B-aligned
#define NGROUP (NIMG*HREF*WREF) // 6400
#define EPS_E 30.25f        // n*alpha^2*sigma^2
#define DE_C 151.25f        // D+E
#define INFD 3.0e38f
#define RTASK (VRAD*9 + VRAD/8)   // 292: task holding the reference candidate

#define FOOT 84             // dn tile: src region == scatter footprint (84x84)
#define FPITCH 85
#define SPITCH 88

// ---------------------------------------------------------------------------
// Stage 1: block matching. Vectorized LDS reads (b128/b64), register top-k.
// ---------------------------------------------------------------------------
__global__ __launch_bounds__(256, 5)
void bm_kernel(const float* __restrict__ y, int* __restrict__ inds)
{
    __shared__ float win[WROWS][WPITCH];   // 25.2 KB
    __shared__ float swv[4];
    __shared__ int   swi[4];

    const int blk = blockIdx.x;
    const int n   = blk / (HREF*WREF);
    const int rem = blk % (HREF*WREF);
    const int hr  = (rem / WREF) * STRIDE_S;
    const int wr  = (rem % WREF) * STRIDE_S;
    const float* img = y + n * HH * WW;
    const int tid = threadIdx.x;

    for (int t = tid; t < WROWS * WPITCH; t += 256) {
        int r = t / WPITCH, c = t % WPITCH;
        int gr = hr - VRAD + r, gc = wr - VRAD + c;
        float v = 0.f;
        if (c < WROWS && gr >= 0 && gr < HH && gc >= 0 && gc < WW)
            v = img[gr * WW + gc];
        win[r][c] = v;
    }
    __syncthreads();

    float d[3][8];
#pragma unroll
    for (int s = 0; s < 3; s++)
#pragma unroll
        for (int c = 0; c < 8; c++) d[s][c] = INFD;

#pragma unroll
    for (int s = 0; s < 3; s++) {
        int task = tid + (s << 8);
        if (task < NTASK) {
            int drx = task / 9;
            int c0  = (task % 9) * 8;
            int rr  = hr + drx - VRAD;
            bool rowok = (rr >= 0 && rr <= HH - PP);
            if (rowok) {
                float dot[8];
                float colsq[18];
#pragma unroll
                for (int c = 0; c < 8; c++) dot[c] = 0.f;
#pragma unroll
                for (int j2 = 0; j2 < 18; j2++) colsq[j2] = 0.f;
                for (int a = 0; a < PP; a++) {
                    const float4* w4 = reinterpret_cast<const float4*>(&win[drx + a][c0]);
                    float4 A0 = w4[0], A1 = w4[1], A2 = w4[2], A3 = w4[3];
                    float2 A4 = *reinterpret_cast<const float2*>(&win[drx + a][c0 + 16]);
                    float wv[18] = {A0.x,A0.y,A0.z,A0.w, A1.x,A1.y,A1.z,A1.w,
                                    A2.x,A2.y,A2.z,A2.w, A3.x,A3.y,A3.z,A3.w,
                                    A4.x,A4.y};
                    const float4* r4 = reinterpret_cast<const float4*>(&win[VRAD + a][VRAD]);
                    float4 R0 = r4[0], R1 = r4[1];
                    float2 R2 = *reinterpret_cast<const float2*>(&win[VRAD + a][VRAD + 8]);
                    float  R3 = win[VRAD + a][VRAD + 10];
                    float rv[11] = {R0.x,R0.y,R0.z,R0.w, R1.x,R1.y,R1.z,R1.w,
                                    R2.x,R2.y, R3};
#pragma unroll
                    for (int j2 = 0; j2 < 18; j2++) colsq[j2] += wv[j2] * wv[j2];
#pragma unroll
                    for (int b = 0; b < PP; b++) {
#pragma unroll
                        for (int c = 0; c < 8; c++)
                            dot[c] += wv[b + c] * rv[b];
                    }
                }
#pragma unroll
                for (int j2 = 1; j2 < 18; j2++) colsq[j2] += colsq[j2 - 1];
#pragma unroll
                for (int c = 0; c < 8; c++) {
                    int dcx = c0 + c;
                    int cc  = wr + dcx - VRAD;
                    float norm = colsq[c + 10] - (c ? colsq[c - 1] : 0.f);
                    if (dcx < WINW && cc >= 0 && cc <= WW - PP)
                        d[s][c] = norm - 2.f * dot[c];
                }
            }
            if (task == RTASK) d[s][0] = -INFD;
        }
    }

    float lval = INFD; int lidx = 0;
#pragma unroll
    for (int s = 0; s < 3; s++)
#pragma unroll
        for (int c = 0; c < 8; c++)
            if (d[s][c] < lval) { lval = d[s][c]; lidx = (s << 3) | c; }

    for (int sel = 0; sel < KSIM; sel++) {
        float rv = lval;
        int   ri = ((tid + ((lidx >> 3) << 8)) << 3) | (lidx & 7);
#pragma unroll
        for (int off = 32; off > 0; off >>= 1) {
            float ov = __shfl_down(rv, off);
            int   oi = __shfl_down(ri, off);
            if (ov < rv) { rv = ov; ri = oi; }
        }
        if ((tid & 63) == 0) { swv[tid >> 6] = rv; swi[tid >> 6] = ri; }
        __syncthreads();
        float bval = swv[0]; int bidx = swi[0];
#pragma unroll
        for (int w2 = 1; w2 < 4; w2++)
            if (swv[w2] < bval) { bval = swv[w2]; bidx = swi[w2]; }
        if (tid == 0) {
            int task = bidx >> 3;
            int drx = task / 9, dcx = (task % 9) * 8 + (bidx & 7);
            int prr = hr + drx - VRAD, pcc = wr + dcx - VRAD;
            inds[blk * KSIM + sel] = prr * NPOS + pcc;
        }
        __syncthreads();
        int otid = (bidx >> 3) & 255;
        if (tid == otid) {
            int code = (((bidx >> 3) >> 8) << 3) | (bidx & 7);
            lval = INFD; lidx = 0;
#pragma unroll
            for (int s = 0; s < 3; s++)
#pragma unroll
                for (int c = 0; c < 8; c++) {
                    if (((s << 3) | c) == code) d[s][c] = INFD;
                    if (d[s][c] < lval) { lval = d[s][c]; lidx = (s << 3) | c; }
                }
        }
    }
}

// ---------------------------------------------------------------------------
// Stage 2+3: tiled denoise, throughput-oriented. One block = 4x4 groups,
// 512 threads. Source region staged in LDS (all Y reads are LDS). Lockstep
// Gauss-Jordan inversion of all 16 Q matrices (no shfl/bpermute). xhat with
// register accumulators; LDS-atomic accumulate; single flush.
// ---------------------------------------------------------------------------
__global__ __launch_bounds__(512, 1)
void dn_kernel(const float* __restrict__ y, const int* __restrict__ inds,
               float2* __restrict__ nd, int R)
{
    __shared__ float  src[FOOT][SPITCH];     // 29.6 KB
    __shared__ float2 acc[FOOT][FPITCH];     // 57.1 KB
    __shared__ float  Qm[16][16][17];        // 17.4 KB (Q -> Qinv -> theta)
    __shared__ float  s1[16][16];
    __shared__ float  s2[16];
    __shared__ float  wl[16][16];
    __shared__ short  pr_[16][16], pc_[16][16];

    const int blk = blockIdx.x;
    const int n  = blk / 100;
    const int tr = blk % 100;
    const int ti = tr / 10, tj = tr % 10;
    const int r0 = 12*ti - VRAD, c0 = 12*tj - VRAD;   // src/acc origin
    const int tid = threadIdx.x;
    const float* img = y + n * HH * WW;

    if (tid < 256) {
        int g = tid >> 4, m = tid & 15;
        int gg = n*(HREF*WREF) + (ti*4 + (g >> 2))*WREF + (tj*4 + (g & 3));
        int idx = inds[gg*KSIM + m];
        pr_[g][m] = (short)(idx / NPOS);
        pc_[g][m] = (short)(idx % NPOS);
    }
    for (int t = tid; t < FOOT*FOOT; t += 512) {
        int rr = t / FOOT, cc = t % FOOT;
        int gr = r0 + rr, gc = c0 + cc;
        float v = 0.f;
        if (gr >= 0 && gr < HH && gc >= 0 && gc < WW) v = img[gr*WW + gc];
        src[rr][cc] = v;
    }
    for (int t = tid; t < FOOT*FPITCH; t += 512)
        acc[t/FPITCH][t%FPITCH] = make_float2(0.f, 0.f);
    __syncthreads();

    // ---- Q: 16 groups x 136 triangle entries = 2176 tasks ----
    for (int k = 0; k < 5; k++) {
        int task = tid + k*512;
        if (task < 16*136) {
            int g = task / 136, e = task % 136;
            int i = (int)((sqrtf(8.f*(float)e + 1.f) - 1.f) * 0.5f + 1e-4f);
            int j = e - i*(i+1)/2;
            int ari = pr_[g][i] - r0, aci = pc_[g][i] - c0;
            int arj = pr_[g][j] - r0, acj = pc_[g][j] - c0;
            float s = (i == j) ? EPS_E : 0.f;
            for (int a = 0; a < PP; a++) {
                const float* Ri = &src[ari + a][aci];
                const float* Rj = &src[arj + a][acj];
#pragma unroll
                for (int b = 0; b < PP; b++) s += Ri[b] * Rj[b];
            }
            Qm[g][i][j] = s;
            Qm[g][j][i] = s;
        }
    }
    __syncthreads();

    // ---- lockstep Gauss-Jordan inversion (16 SPD matrices, no pivoting) ----
    const int uu = tid >> 8, ii = (tid >> 4) & 15, jj = tid & 15;
    for (int ks = 0; ks < 16; ks++) {
        float fA[8], rk[8], pv[8], aij[8];
#pragma unroll
        for (int k = 0; k < 8; k++) {
            int g = uu + 2*k;
            fA[k]  = Qm[g][ii][ks];
            rk[k]  = Qm[g][ks][jj];
            pv[k]  = Qm[g][ks][ks];
            aij[k] = Qm[g][ii][jj];
        }
        __syncthreads();
#pragma unroll
        for (int k = 0; k < 8; k++) {
            int g = uu + 2*k;
            float inv = 1.f / pv[k];
            float nv;
            if (ii == ks) nv = (jj == ks) ? inv : rk[k] * inv;
            else          nv = (jj == ks) ? -fA[k] * inv : aij[k] - fA[k] * rk[k] * inv;
            Qm[g][ii][jj] = nv;
        }
        __syncthreads();
    }

    // ---- s1, s2, theta (in-place overwrite), weights ----
    if (tid < 256) {
        int g = tid >> 4, a = tid & 15;
        float s = 0.f;
#pragma unroll
        for (int b = 0; b < 16; b++) s += Qm[g][a][b];
        s1[g][a] = s;
    }
    __syncthreads();
    if (tid < 16) {
        float s = 0.f;
#pragma unroll
        for (int a = 0; a < 16; a++) s += s1[tid][a];
        s2[tid] = s;
    }
    __syncthreads();
#pragma unroll
    for (int k = 0; k < 8; k++) {
        int g = uu + 2*k;
        float t = ((ii == jj) ? 1.f : 0.f)
                - (Qm[g][ii][jj] - s1[g][ii]*s1[g][jj]/s2[g]) * DE_C;
        Qm[g][ii][jj] = t;     // each thread owns its (g,ii,jj): no hazard
    }
    __syncthreads();
    if (tid < 256) {
        int g = tid >> 4, r = tid & 15;
        float s = 0.f;
#pragma unroll
        for (int m2 = 0; m2 < 16; m2++) { float t = Qm[g][m2][r]; s += t*t; }
        s = fminf(fmaxf(s, 1.f/16.f), 1.f);
        wl[g][r] = 1.f / s;
    }
    __syncthreads();

    // ---- xhat + LDS scatter: 32 threads per group, 4 pixels each ----
    {
        const int g6 = tid >> 5, q6 = tid & 31;
        const int pxb = q6 * 4;
        int drp[4], dcp[4]; bool okp[4];
#pragma unroll
        for (int p = 0; p < 4; p++) {
            int px = pxb + p;
            okp[p] = (px < 121);
            int pxc = okp[p] ? px : 0;
            drp[p] = pxc / 11; dcp[p] = pxc % 11;
        }
        float xh[16][4];
#pragma unroll
        for (int r = 0; r < 16; r++)
#pragma unroll
            for (int p = 0; p < 4; p++) xh[r][p] = 0.f;
#pragma unroll
        for (int m2 = 0; m2 < 16; m2++) {
            int ar = pr_[g6][m2] - r0, ac = pc_[g6][m2] - c0;
            float tv[16];
#pragma unroll
            for (int r = 0; r < 16; r++) tv[r] = Qm[g6][m2][r];  // broadcast
            float yv[4];
#pragma unroll
            for (int p = 0; p < 4; p++) yv[p] = src[ar + drp[p]][ac + dcp[p]];
#pragma unroll
            for (int r = 0; r < 16; r++)
#pragma unroll
                for (int p = 0; p < 4; p++) xh[r][p] += tv[r] * yv[p];
        }
#pragma unroll
        for (int r = 0; r < 16; r++) {
            int ar = pr_[g6][r] - r0, ac = pc_[g6][r] - c0;
            float wv2 = wl[g6][r];
#pragma unroll
            for (int p = 0; p < 4; p++) {
                if (okp[p]) {
                    float* cell = (float*)&acc[ar + drp[p]][ac + dcp[p]];
                    __hip_atomic_fetch_add(cell,     wv2 * xh[r][p],
                        __ATOMIC_RELAXED, __HIP_MEMORY_SCOPE_WORKGROUP);
                    __hip_atomic_fetch_add(cell + 1, wv2,
                        __ATOMIC_RELAXED, __HIP_MEMORY_SCOPE_WORKGROUP);
                }
            }
        }
    }
    __syncthreads();

    // ---- flush tile to global (skip empty cells) ----
    float2* ndI = nd + ((size_t)(blk & (R - 1)) * NIMG + n) * HH * WW;
    for (int t = tid; t < FOOT * FOOT; t += 512) {
        int rr = t / FOOT, cc = t % FOOT;
        float2 v = acc[rr][cc];
        if (v.y != 0.f) {
            int px = (r0 + rr) * WW + (c0 + cc);
#if defined(__has_builtin) && __has_builtin(__builtin_amdgcn_global_atomic_fadd_v2f32)
            typedef float v2f __attribute__((ext_vector_type(2)));
            __builtin_amdgcn_global_atomic_fadd_v2f32((v2f*)&ndI[px], (v2f){v.x, v.y});
#else
            atomicAdd(&ndI[px].x, v.x);
            atomicAdd(&ndI[px].y, v.y);
#endif
        }
    }
}

// ---------------------------------------------------------------------------
// Stage 4: out = sum_r num_r / sum_r den_r
// ---------------------------------------------------------------------------
__global__ __launch_bounds__(256)
void fin_kernel(const float2* __restrict__ nd, float* __restrict__ out, int R)
{
    int t = blockIdx.x * 256 + threadIdx.x;
    if (t < NIMG * HH * WW) {
        float sn = 0.f, sd = 0.f;
        for (int r = 0; r < R; r++) {
            float2 v = nd[(size_t)r * NIMG * HH * WW + t];
            sn += v.x; sd += v.y;
        }
        out[t] = sn / sd;
    }
}

extern "C" void kernel_launch(void* const* d_in, const int* in_sizes, int n_in,
                              void* d_out, int out_size, void* d_ws, size_t ws_size,
                              hipStream_t stream)
{
    const float* y = (const float*)d_in[0];
    float* out = (float*)d_out;

    size_t indsBytes = (size_t)NGROUP * KSIM * sizeof(int);
    size_t perRep    = (size_t)NIMG * HH * WW * sizeof(float2);
    int R = 1;
    while (R < 4 && indsBytes + perRep * (size_t)(R * 2) <= ws_size) R <<= 1;

    float2* nd  = (float2*)d_ws;
    int*    inds = (int*)((char*)d_ws + perRep * (size_t)R);

    hipMemsetAsync(nd, 0, perRep * (size_t)R, stream);
    bm_kernel<<<NGROUP, 256, 0, stream>>>(y, inds);
    dn_kernel<<<NIMG * 100, 512, 0, stream>>>(y, inds, nd, R);
    fin_kernel<<<(NIMG * HH * WW + 255) / 256, 256, 0, stream>>>(nd, out, R);
}